// Round 6
// baseline (1765.661 us; speedup 1.0000x reference)
//
#include <hip/hip_runtime.h>

#define FDIM 128
#define PH_SHIFT 13
#define PH_ROWS  (1 << PH_SHIFT)      // 8192 rows/phase -> 2MB bf16 slice < 4MB L2/XCD
#define NWAVES   8192                 // persistent waves: 256CU x 4SIMD x 8 waves
#define RPW      13                   // rows per wave; RPW*NWAVES=106496 >= N=100000

typedef __attribute__((ext_vector_type(8))) short short8v;   // 8 bf16
typedef __attribute__((ext_vector_type(4))) float f32x4;

// ---------- bf16 helpers (manual, RNE) ----------
__device__ __forceinline__ uint16_t f2bf(float f) {
    uint32_t u = __float_as_uint(f);
    uint32_t r = (u + 0x7fffu + ((u >> 16) & 1u)) >> 16;
    return (uint16_t)r;
}
__device__ __forceinline__ uint32_t pack_bf16(float a, float b) {
    return (uint32_t)f2bf(a) | ((uint32_t)f2bf(b) << 16);
}
__device__ __forceinline__ float bflo(uint32_t u) { return __uint_as_float(u << 16); }
__device__ __forceinline__ float bfhi(uint32_t u) { return __uint_as_float(u & 0xffff0000u); }
// scalarize a float WITHOUT value conversion (readfirstlane is i32-typed!)
__device__ __forceinline__ float rfl_f32(float v) {
    return __uint_as_float(__builtin_amdgcn_readfirstlane(__float_as_uint(v)));
}

// ---------------------------------------------------------------------------
// Kernel 1: row_ptr[i] = lower_bound(rows, i). rows sorted.
// ---------------------------------------------------------------------------
__global__ __launch_bounds__(256) void build_row_ptr_k(const int* __restrict__ rows,
                                                       int E, int N,
                                                       int* __restrict__ rp) {
    int i = blockIdx.x * 256 + threadIdx.x;
    if (i > N) return;
    int lo = 0, hi = E;
    while (lo < hi) {
        int mid = (lo + hi) >> 1;
        if (rows[mid] < i) lo = mid + 1; else hi = mid;
    }
    rp[i] = lo;
}

// ---------------------------------------------------------------------------
// Kernel 1b: Wt[n][k] = bf16(W[k][n]), 128x128.
// ---------------------------------------------------------------------------
__global__ __launch_bounds__(256) void transpose_w_k(const float* __restrict__ W,
                                                     uint16_t* __restrict__ Wt) {
    int idx = blockIdx.x * 256 + threadIdx.x;   // 0..16383
    int k = idx >> 7, n = idx & 127;
    Wt[n * FDIM + k] = f2bf(W[k * FDIM + n]);
}

// ---------------------------------------------------------------------------
// Kernel 1c: per-row counting sort of edges by column phase (col >> PH_SHIFT).
// One wave per row; fast ballot path for deg<=64, serial fallback otherwise.
// Any order within (row,phase) is fine; phases must be monotone within row.
// ---------------------------------------------------------------------------
__global__ __launch_bounds__(256) void reorder_k(const int* __restrict__ rp,
                                                 const int* __restrict__ cols,
                                                 const float* __restrict__ vals,
                                                 int* __restrict__ cols2,
                                                 float* __restrict__ vals2,
                                                 int N, int nphase) {
    int r    = (blockIdx.x * 256 + threadIdx.x) >> 6;
    int lane = threadIdx.x & 63;
    if (r >= N) return;
    int s = __builtin_amdgcn_readfirstlane(rp[r]);
    int e = __builtin_amdgcn_readfirstlane(rp[r + 1]);
    int deg = e - s;
    if (deg <= 0) return;

    if (deg <= 64) {
        bool valid = lane < deg;
        int   c = valid ? cols[s + lane] : 0x7fffffff;
        float v = valid ? vals[s + lane] : 0.f;
        int  ph = c >> PH_SHIFT;              // invalid lanes: huge, never matches
        int base = s;
        for (int p = 0; p < nphase; ++p) {
            unsigned long long m = __ballot(ph == p);
            int pref = __popcll(m & ((1ull << lane) - 1ull));
            if (ph == p) { cols2[base + pref] = c; vals2[base + pref] = v; }
            base += __popcll(m);
        }
    } else {
        // rare (Poisson(32) tail): serial, stable
        if (lane == 0) {
            int base = s;
            for (int p = 0; p < nphase; ++p)
                for (int i = s; i < e; ++i) {
                    int c = cols[i];
                    if ((c >> PH_SHIFT) == p) { cols2[base] = c; vals2[base] = vals[i]; ++base; }
                }
        }
    }
}

// ---------------------------------------------------------------------------
// Kernel 2: C = A @ W via bf16 MFMA 16x16x32 (round-3 version, row-major bf16).
// ---------------------------------------------------------------------------
template <int ABF>
__global__ __launch_bounds__(256) void gemm_mfma_k(const void* __restrict__ A_,
                                                   const uint16_t* __restrict__ Wt,
                                                   uint16_t* __restrict__ C, int M) {
    const int t = threadIdx.x;
    const int w = t >> 6;
    const int l = t & 63;
    const int row0 = blockIdx.x * 128 + w * 32;

    f32x4 acc[2][8];
#pragma unroll
    for (int mf = 0; mf < 2; ++mf)
#pragma unroll
        for (int nf = 0; nf < 8; ++nf) acc[mf][nf] = (f32x4)0.f;

    const int lr = l & 15;
    const int kg = l >> 4;

#pragma unroll
    for (int ks = 0; ks < 4; ++ks) {
        const int k0 = ks * 32 + kg * 8;
        short8v a[2];
#pragma unroll
        for (int mf = 0; mf < 2; ++mf) {
            int r = row0 + mf * 16 + lr;
            if (r >= M) r = M - 1;      // safe clamp; stores guarded
            if constexpr (ABF) {
                a[mf] = *(const short8v*)((const uint16_t*)A_ + (size_t)r * FDIM + k0);
            } else {
                const float* ap = (const float*)A_ + (size_t)r * FDIM + k0;
                float4 f0 = *(const float4*)(ap);
                float4 f1 = *(const float4*)(ap + 4);
                uint32_t p0 = pack_bf16(f0.x, f0.y), p1 = pack_bf16(f0.z, f0.w);
                uint32_t p2 = pack_bf16(f1.x, f1.y), p3 = pack_bf16(f1.z, f1.w);
                uint4 u = make_uint4(p0, p1, p2, p3);
                a[mf] = *(short8v*)&u;
            }
        }
#pragma unroll
        for (int nf = 0; nf < 8; ++nf) {
            short8v b = *(const short8v*)(Wt + (size_t)(nf * 16 + lr) * FDIM + k0);
            acc[0][nf] = __builtin_amdgcn_mfma_f32_16x16x32_bf16(a[0], b, acc[0][nf], 0, 0, 0);
            acc[1][nf] = __builtin_amdgcn_mfma_f32_16x16x32_bf16(a[1], b, acc[1][nf], 0, 0, 0);
        }
    }

    const int colpar = l & 1;
#pragma unroll
    for (int mf = 0; mf < 2; ++mf) {
#pragma unroll
        for (int nf = 0; nf < 8; ++nf) {
            int col = nf * 16 + lr;
#pragma unroll
            for (int j = 0; j < 4; ++j) {
                float v = acc[mf][nf][j];
                float pv = __shfl_xor(v, 1);
                int row = row0 + mf * 16 + kg * 4 + j;
                if (!colpar && row < M) {
                    *(uint32_t*)(C + (size_t)row * FDIM + col) = pack_bf16(v, pv);
                }
            }
        }
    }
}

// ---------------------------------------------------------------------------
// Kernel 3: phase-blocked SPMM. Persistent 8192 waves; wave w owns rows
// {w, w+8192, ...} (RPW=13), accumulators + cursors in registers. Outer loop
// over column phases; per phase each row scans its phase-sorted edge segment.
// Gather = one 256B contiguous row read (L2-resident: 2MB phase slice).
// ---------------------------------------------------------------------------
template <int RELU, int OBF>
__global__ __launch_bounds__(256, 8) void spmm_phase_k(const int* __restrict__ rp,
                                                       const int* __restrict__ cols2,
                                                       const float* __restrict__ vals2,
                                                       const uint32_t* __restrict__ X, // bf16x2 rows
                                                       const float* __restrict__ bias,
                                                       void* __restrict__ out,
                                                       int N, int nphase) {
    const int w    = (blockIdx.x * 256 + threadIdx.x) >> 6;   // 0..8191
    const int lane = threadIdx.x & 63;

    int   cur[RPW], end[RPW];
    float ax[RPW], ay[RPW];
#pragma unroll
    for (int j = 0; j < RPW; ++j) {
        int r = w + j * NWAVES;
        if (r < N) {
            cur[j] = __builtin_amdgcn_readfirstlane(rp[r]);
            end[j] = __builtin_amdgcn_readfirstlane(rp[r + 1]);
        } else { cur[j] = 0; end[j] = 0; }
        ax[j] = 0.f; ay[j] = 0.f;
    }

    for (int p = 0; p < nphase; ++p) {
#pragma unroll
        for (int j = 0; j < RPW; ++j) {
            int cu = cur[j];
            const int en = end[j];
            float alo = ax[j], ahi = ay[j];
            while (cu < en) {
                int c = __builtin_amdgcn_readfirstlane(cols2[cu]);
                if ((c >> PH_SHIFT) != p) break;            // wave-uniform
                float v = rfl_f32(vals2[cu]);               // bit-cast scalarize!
                uint32_t u = X[(size_t)c * 64 + lane];      // 256B contiguous
                alo = fmaf(v, bflo(u), alo);
                ahi = fmaf(v, bfhi(u), ahi);
                ++cu;
            }
            cur[j] = cu; ax[j] = alo; ay[j] = ahi;
        }
    }

    const float2 bb = *(const float2*)(bias + 2 * lane);
#pragma unroll
    for (int j = 0; j < RPW; ++j) {
        int r = w + j * NWAVES;
        if (r >= N) continue;
        float ox = ax[j] + bb.x, oy = ay[j] + bb.y;
        if (RELU) { ox = fmaxf(ox, 0.f); oy = fmaxf(oy, 0.f); }
        if constexpr (OBF) {
            ((uint32_t*)out)[(size_t)r * 64 + lane] = pack_bf16(ox, oy);
        } else {
            *(float2*)((float*)out + (size_t)r * FDIM + 2 * lane) = make_float2(ox, oy);
        }
    }
}

// ---------------------------------------------------------------------------
extern "C" void kernel_launch(void* const* d_in, const int* in_sizes, int n_in,
                              void* d_out, int out_size, void* d_ws, size_t ws_size,
                              hipStream_t stream) {
    const float* features = (const float*)d_in[0];
    const int*   adj_rows = (const int*)d_in[1];
    const int*   adj_cols = (const int*)d_in[2];
    const float* adj_vals = (const float*)d_in[3];
    const float* W1       = (const float*)d_in[4];
    const float* b1       = (const float*)d_in[5];
    const float* W2       = (const float*)d_in[6];
    const float* b2       = (const float*)d_in[7];

    const int N = in_sizes[0] / FDIM;    // 100000
    const int E = in_sizes[1];           // 3200000
    float* out = (float*)d_out;
    const int nphase = (N + PH_ROWS - 1) >> PH_SHIFT;   // 13

    // ws layout (~77.5 MB; round 1 proved >=103 MB available)
    char* ws = (char*)d_ws;
    int* rp = (int*)ws;
    size_t rp_bytes = (((size_t)(N + 1) * sizeof(int)) + 255) & ~(size_t)255;
    int*      cols2 = (int*)(ws + rp_bytes);                 // E + pad
    size_t    e_pad = ((size_t)E + 64) * sizeof(int);
    float*    vals2 = (float*)((char*)cols2 + e_pad);
    uint16_t* XWb   = (uint16_t*)((char*)vals2 + e_pad);     // N*128 bf16 (25.6 MB)
    uint16_t* Hb    = XWb + (size_t)N * FDIM;                // N*128 bf16 (25.6 MB)
    uint16_t* W1t   = Hb + (size_t)N * FDIM;                 // 32 KB
    uint16_t* W2t   = W1t + FDIM * FDIM;                     // 32 KB

    const int nblk_gemm = (N + 127) / 128;
    const int nblk_spmm = NWAVES / 4;    // 2048 blocks x 4 waves = 8192 waves

    // 1. CSR row_ptr + W transposes
    build_row_ptr_k<<<(N + 256) / 256, 256, 0, stream>>>(adj_rows, E, N, rp);
    transpose_w_k<<<64, 256, 0, stream>>>(W1, W1t);
    transpose_w_k<<<64, 256, 0, stream>>>(W2, W2t);
    // 1c. phase-sort edges within each row (serves both SPMMs)
    reorder_k<<<(N * 64 + 255) / 256, 256, 0, stream>>>(rp, adj_cols, adj_vals,
                                                        cols2, vals2, N, nphase);
    // 2. XWb = bf16(X @ W1)
    gemm_mfma_k<0><<<nblk_gemm, 256, 0, stream>>>((const void*)features, W1t, XWb, N);
    // 3. Hb = bf16(relu(A @ XWb + b1))
    spmm_phase_k<1, 1><<<nblk_spmm, 256, 0, stream>>>(rp, cols2, vals2,
                                                      (const uint32_t*)XWb, b1, (void*)Hb,
                                                      N, nphase);
    // 4. XWb = bf16(Hb @ W2)
    gemm_mfma_k<1><<<nblk_gemm, 256, 0, stream>>>((const void*)Hb, W2t, XWb, N);
    // 5. out = A @ XWb + b2  (f32)
    spmm_phase_k<0, 0><<<nblk_spmm, 256, 0, stream>>>(rp, cols2, vals2,
                                                      (const uint32_t*)XWb, b2, (void*)out,
                                                      N, nphase);
}

// Round 7
// 899.985 us; speedup vs baseline: 1.9619x; 1.9619x over previous
//
#include <hip/hip_runtime.h>

#define FDIM 128
#define PH_SHIFT 13
#define PH_ROWS  (1 << PH_SHIFT)     // 8192 rows/phase -> 2MB bf16 slice < 4MB L2/XCD
#define NPH      13                  // ceil(102400/8192)
#define RPW2     25                  // contiguous rows per wave
#define NWAVE2   4096                // 1024 blocks x 4 waves (all resident at occ 4/SIMD)
#define NP       (NWAVE2 * RPW2)     // 102400 padded rows
#define LTAB     (NPH * NP + 1)      // 1331201 (exclusive-scan table + sentinel)
#define SCAN_CH  2048
#define SCAN_NB  ((LTAB + SCAN_CH - 1) / SCAN_CH)   // 651 (must be <= 1024)

typedef __attribute__((ext_vector_type(8))) short short8v;   // 8 bf16
typedef __attribute__((ext_vector_type(4))) float f32x4;

// ---------- bf16 helpers (manual, RNE) ----------
__device__ __forceinline__ uint16_t f2bf(float f) {
    uint32_t u = __float_as_uint(f);
    uint32_t r = (u + 0x7fffu + ((u >> 16) & 1u)) >> 16;
    return (uint16_t)r;
}
__device__ __forceinline__ uint32_t pack_bf16(float a, float b) {
    return (uint32_t)f2bf(a) | ((uint32_t)f2bf(b) << 16);
}
__device__ __forceinline__ float bflo(uint32_t u) { return __uint_as_float(u << 16); }
__device__ __forceinline__ float bfhi(uint32_t u) { return __uint_as_float(u & 0xffff0000u); }

// ---------------------------------------------------------------------------
// Wt[n][k] = bf16(W[k][n]), 128x128.
// ---------------------------------------------------------------------------
__global__ __launch_bounds__(256) void transpose_w_k(const float* __restrict__ W,
                                                     uint16_t* __restrict__ Wt) {
    int idx = blockIdx.x * 256 + threadIdx.x;   // 0..16383
    int k = idx >> 7, n = idx & 127;
    Wt[n * FDIM + k] = f2bf(W[k * FDIM + n]);
}

// ---------------------------------------------------------------------------
// Preprocessing: (phase,row)-major CSR over edges.
// ---------------------------------------------------------------------------
__global__ __launch_bounds__(256) void zero_k(uint32_t* __restrict__ a, int n) {
    int i = blockIdx.x * 256 + threadIdx.x;
    if (i < n) a[i] = 0u;
}

__global__ __launch_bounds__(256) void cnt_k(const int* __restrict__ rows,
                                             const int* __restrict__ cols, int E,
                                             uint32_t* __restrict__ cnt) {
    int e = blockIdx.x * 256 + threadIdx.x;
    if (e >= E) return;
    int r = rows[e];
    int p = cols[e] >> PH_SHIFT;
    atomicAdd(&cnt[(size_t)p * NP + r], 1u);
}

// scan step 1: per-block (2048-elem chunk) sums
__global__ __launch_bounds__(256) void scan1_k(const uint32_t* __restrict__ cnt,
                                               uint32_t* __restrict__ part) {
    __shared__ uint32_t sb[256];
    int b = blockIdx.x, t = threadIdx.x;
    size_t base = (size_t)b * SCAN_CH + (size_t)t * 8;
    uint32_t s = 0;
#pragma unroll
    for (int k = 0; k < 8; ++k)
        if (base + k < LTAB) s += cnt[base + k];
    sb[t] = s; __syncthreads();
    for (int off = 128; off > 0; off >>= 1) {
        if (t < off) sb[t] += sb[t + off];
        __syncthreads();
    }
    if (t == 0) part[b] = sb[0];
}

// scan step 2: exclusive scan of the 651 partials, one 1024-thread block
__global__ __launch_bounds__(1024) void scan2_k(uint32_t* __restrict__ part) {
    __shared__ uint32_t sb[1024];
    int t = threadIdx.x;
    uint32_t x = (t < SCAN_NB) ? part[t] : 0u;
    sb[t] = x; __syncthreads();
    for (int off = 1; off < 1024; off <<= 1) {
        uint32_t v = (t >= off) ? sb[t - off] : 0u;
        __syncthreads();
        sb[t] += v;
        __syncthreads();
    }
    if (t < SCAN_NB) part[t] = sb[t] - x;   // exclusive
}

// scan step 3: final exclusive scan, in-place over cnt (-> ptr3), copy to cur3
__global__ __launch_bounds__(256) void scan3_k(uint32_t* __restrict__ cnt,   // in: counts, out: ptr3
                                               const uint32_t* __restrict__ part,
                                               uint32_t* __restrict__ cur3) {
    __shared__ uint32_t sb[256];
    int b = blockIdx.x, t = threadIdx.x;
    size_t base = (size_t)b * SCAN_CH + (size_t)t * 8;
    uint32_t v[8], ex[8], run = 0;
#pragma unroll
    for (int k = 0; k < 8; ++k) {
        v[k] = (base + k < LTAB) ? cnt[base + k] : 0u;
        ex[k] = run; run += v[k];
    }
    sb[t] = run; __syncthreads();
    for (int off = 1; off < 256; off <<= 1) {
        uint32_t w = (t >= off) ? sb[t - off] : 0u;
        __syncthreads();
        sb[t] += w;
        __syncthreads();
    }
    uint32_t toff = sb[t] - run + part[b];   // block offset + exclusive thread offset
#pragma unroll
    for (int k = 0; k < 8; ++k) {
        if (base + k < LTAB) {
            uint32_t val = toff + ex[k];
            cnt[base + k]  = val;
            cur3[base + k] = val;
        }
    }
}

// scatter edges into (phase,row)-major order; 4B/edge: low13=col&8191, hi16=bf16(val)
__global__ __launch_bounds__(256) void scatter_k(const int* __restrict__ rows,
                                                 const int* __restrict__ cols,
                                                 const float* __restrict__ vals, int E,
                                                 uint32_t* __restrict__ cur3,
                                                 uint32_t* __restrict__ edge3) {
    int e = blockIdx.x * 256 + threadIdx.x;
    if (e < E) {
        int r = rows[e], c = cols[e];
        int p = c >> PH_SHIFT;
        uint32_t pos = atomicAdd(&cur3[(size_t)p * NP + r], 1u);
        edge3[pos] = (uint32_t)(c & (PH_ROWS - 1)) | ((uint32_t)f2bf(vals[e]) << 16);
    } else if (e < E + 64) {
        edge3[e] = 0u;            // pad window reads
    }
}

// ---------------------------------------------------------------------------
// GEMM: C = A @ W via bf16 MFMA 16x16x32 (round-3 validated).
// ---------------------------------------------------------------------------
template <int ABF>
__global__ __launch_bounds__(256) void gemm_mfma_k(const void* __restrict__ A_,
                                                   const uint16_t* __restrict__ Wt,
                                                   uint16_t* __restrict__ C, int M) {
    const int t = threadIdx.x;
    const int w = t >> 6;
    const int l = t & 63;
    const int row0 = blockIdx.x * 128 + w * 32;

    f32x4 acc[2][8];
#pragma unroll
    for (int mf = 0; mf < 2; ++mf)
#pragma unroll
        for (int nf = 0; nf < 8; ++nf) acc[mf][nf] = (f32x4)0.f;

    const int lr = l & 15;
    const int kg = l >> 4;

#pragma unroll
    for (int ks = 0; ks < 4; ++ks) {
        const int k0 = ks * 32 + kg * 8;
        short8v a[2];
#pragma unroll
        for (int mf = 0; mf < 2; ++mf) {
            int r = row0 + mf * 16 + lr;
            if (r >= M) r = M - 1;      // safe clamp; stores guarded
            if constexpr (ABF) {
                a[mf] = *(const short8v*)((const uint16_t*)A_ + (size_t)r * FDIM + k0);
            } else {
                const float* ap = (const float*)A_ + (size_t)r * FDIM + k0;
                float4 f0 = *(const float4*)(ap);
                float4 f1 = *(const float4*)(ap + 4);
                uint32_t p0 = pack_bf16(f0.x, f0.y), p1 = pack_bf16(f0.z, f0.w);
                uint32_t p2 = pack_bf16(f1.x, f1.y), p3 = pack_bf16(f1.z, f1.w);
                uint4 u = make_uint4(p0, p1, p2, p3);
                a[mf] = *(short8v*)&u;
            }
        }
#pragma unroll
        for (int nf = 0; nf < 8; ++nf) {
            short8v b = *(const short8v*)(Wt + (size_t)(nf * 16 + lr) * FDIM + k0);
            acc[0][nf] = __builtin_amdgcn_mfma_f32_16x16x32_bf16(a[0], b, acc[0][nf], 0, 0, 0);
            acc[1][nf] = __builtin_amdgcn_mfma_f32_16x16x32_bf16(a[1], b, acc[1][nf], 0, 0, 0);
        }
    }

    const int colpar = l & 1;
#pragma unroll
    for (int mf = 0; mf < 2; ++mf) {
#pragma unroll
        for (int nf = 0; nf < 8; ++nf) {
            int col = nf * 16 + lr;
#pragma unroll
            for (int j = 0; j < 4; ++j) {
                float v = acc[mf][nf][j];
                float pv = __shfl_xor(v, 1);
                int row = row0 + mf * 16 + kg * 4 + j;
                if (!colpar && row < M) {
                    *(uint32_t*)(C + (size_t)row * FDIM + col) = pack_bf16(v, pv);
                }
            }
        }
    }
}

// ---------------------------------------------------------------------------
// Phase-blocked SPMM v2. 1024 blocks x 4 waves, all resident (occ 4/SIMD).
// Wave owns 25 contiguous rows; per phase consumes its contiguous edge run
// via a 64-edge register window (shfl extraction, no per-edge uniform loads).
// Gather = contiguous 256B X row, L2-resident (2MB phase slice).
// ---------------------------------------------------------------------------
template <int RELU, int OBF>
__global__ __launch_bounds__(256, 4) void spmm2_k(const uint32_t* __restrict__ ptr3,
                                                  const uint32_t* __restrict__ edge3,
                                                  const uint32_t* __restrict__ X,  // bf16x2 rows
                                                  const float* __restrict__ bias,
                                                  void* __restrict__ out, int N) {
    const int wid  = (blockIdx.x * 256 + threadIdx.x) >> 6;   // 0..4095
    const int lane = threadIdx.x & 63;
    const int r0   = wid * RPW2;

    float ax[RPW2], ay[RPW2];
#pragma unroll
    for (int j = 0; j < RPW2; ++j) { ax[j] = 0.f; ay[j] = 0.f; }

    for (int p = 0; p < NPH; ++p) {
        // boundary vector: lane j holds ptr3[p][r0+j], j=0..25
        int bl = lane <= RPW2 ? lane : RPW2;
        int bv = (int)ptr3[(size_t)p * NP + r0 + bl];
        const size_t xbase = (size_t)p << PH_SHIFT;   // first row of this phase

        int W = -0x40000000;      // force initial window load
        uint32_t wv = 0;
#pragma unroll
        for (int j = 0; j < RPW2; ++j) {
            int s = __shfl(bv, j);
            int e = __shfl(bv, j + 1);
            float alo = ax[j], ahi = ay[j];
            for (int i = s; i < e; ++i) {
                if (i >= W + 64) { W = i; wv = edge3[W + lane]; }   // wave-uniform
                uint32_t ew = (uint32_t)__shfl((int)wv, i - W);
                float v = bfhi(ew);
                uint32_t u = X[(xbase + (ew & (PH_ROWS - 1))) * 64 + lane];
                alo = fmaf(v, bflo(u), alo);
                ahi = fmaf(v, bfhi(u), ahi);
            }
            ax[j] = alo; ay[j] = ahi;
        }
    }

    const float2 bb = *(const float2*)(bias + 2 * lane);
#pragma unroll
    for (int j = 0; j < RPW2; ++j) {
        int r = r0 + j;
        if (r >= N) continue;
        float ox = ax[j] + bb.x, oy = ay[j] + bb.y;
        if (RELU) { ox = fmaxf(ox, 0.f); oy = fmaxf(oy, 0.f); }
        if constexpr (OBF) {
            ((uint32_t*)out)[(size_t)r * 64 + lane] = pack_bf16(ox, oy);
        } else {
            *(float2*)((float*)out + (size_t)r * FDIM + 2 * lane) = make_float2(ox, oy);
        }
    }
}

// ---------------------------------------------------------------------------
extern "C" void kernel_launch(void* const* d_in, const int* in_sizes, int n_in,
                              void* d_out, int out_size, void* d_ws, size_t ws_size,
                              hipStream_t stream) {
    const float* features = (const float*)d_in[0];
    const int*   adj_rows = (const int*)d_in[1];
    const int*   adj_cols = (const int*)d_in[2];
    const float* adj_vals = (const float*)d_in[3];
    const float* W1       = (const float*)d_in[4];
    const float* b1       = (const float*)d_in[5];
    const float* W2       = (const float*)d_in[6];
    const float* b2       = (const float*)d_in[7];

    const int N = in_sizes[0] / FDIM;    // 100000
    const int E = in_sizes[1];           // 3200000
    float* out = (float*)d_out;

    // ws layout (~75 MB)
    char* ws = (char*)d_ws;
    uint32_t* edge3 = (uint32_t*)ws;                          // (E+64)*4   = 12.8 MB
    size_t   e3_b   = (((size_t)(E + 64) * 4) + 255) & ~(size_t)255;
    uint32_t* ptr3  = (uint32_t*)(ws + e3_b);                 // LTAB*4     = 5.33 MB (counts -> scan in place)
    size_t   tb_b   = (((size_t)LTAB * 4) + 255) & ~(size_t)255;
    uint32_t* cur3  = (uint32_t*)((char*)ptr3 + tb_b);        // LTAB*4     = 5.33 MB
    uint32_t* part  = (uint32_t*)((char*)cur3 + tb_b);        // SCAN_NB*4
    size_t   pt_b   = (((size_t)SCAN_NB * 4) + 255) & ~(size_t)255;
    uint16_t* XWb   = (uint16_t*)((char*)part + pt_b);        // N*128 bf16 = 25.6 MB
    uint16_t* Hb    = XWb + (size_t)N * FDIM;                 // N*128 bf16 = 25.6 MB
    uint16_t* W1t   = Hb + (size_t)N * FDIM;                  // 32 KB
    uint16_t* W2t   = W1t + FDIM * FDIM;                      // 32 KB

    const int nblk_gemm = (N + 127) / 128;

    // --- preprocessing: (phase,row)-major edge CSR (runs every call) ---
    transpose_w_k<<<64, 256, 0, stream>>>(W1, W1t);
    transpose_w_k<<<64, 256, 0, stream>>>(W2, W2t);
    zero_k<<<(LTAB + 255) / 256, 256, 0, stream>>>(ptr3, LTAB);
    cnt_k<<<(E + 255) / 256, 256, 0, stream>>>(adj_rows, adj_cols, E, ptr3);
    scan1_k<<<SCAN_NB, 256, 0, stream>>>(ptr3, part);
    scan2_k<<<1, 1024, 0, stream>>>(part);
    scan3_k<<<SCAN_NB, 256, 0, stream>>>(ptr3, part, cur3);
    scatter_k<<<(E + 64 + 255) / 256, 256, 0, stream>>>(adj_rows, adj_cols, adj_vals,
                                                        E, cur3, edge3);
    // --- layer 1 ---
    gemm_mfma_k<0><<<nblk_gemm, 256, 0, stream>>>((const void*)features, W1t, XWb, N);
    spmm2_k<1, 1><<<NWAVE2 / 4, 256, 0, stream>>>(ptr3, edge3, (const uint32_t*)XWb,
                                                  b1, (void*)Hb, N);
    // --- layer 2 ---
    gemm_mfma_k<1><<<nblk_gemm, 256, 0, stream>>>((const void*)Hb, W2t, XWb, N);
    spmm2_k<0, 0><<<NWAVE2 / 4, 256, 0, stream>>>(ptr3, edge3, (const uint32_t*)XWb,
                                                  b2, (void*)out, N);
}

// Round 9
// 359.272 us; speedup vs baseline: 4.9146x; 2.5050x over previous
//
#include <hip/hip_runtime.h>

#define FDIM 128
#define PH_SHIFT 13          // phase = col >> 13 (8192 rows = 2MB bf16 X-slice)
#define NPH 13

typedef __attribute__((ext_vector_type(8))) short short8v;   // 8 bf16
typedef __attribute__((ext_vector_type(4))) float f32x4;

// ---------- bf16 helpers (manual, RNE) ----------
__device__ __forceinline__ uint16_t f2bf(float f) {
    uint32_t u = __float_as_uint(f);
    uint32_t r = (u + 0x7fffu + ((u >> 16) & 1u)) >> 16;
    return (uint16_t)r;
}
__device__ __forceinline__ uint32_t pack_bf16(float a, float b) {
    return (uint32_t)f2bf(a) | ((uint32_t)f2bf(b) << 16);
}
__device__ __forceinline__ float bflo(uint32_t u) { return __uint_as_float(u << 16); }
__device__ __forceinline__ float bfhi(uint32_t u) { return __uint_as_float(u & 0xffff0000u); }

// ---------------------------------------------------------------------------
// row_ptr[i] = lower_bound(rows, i). rows sorted.
// ---------------------------------------------------------------------------
__global__ __launch_bounds__(256) void build_row_ptr_k(const int* __restrict__ rows,
                                                       int E, int N,
                                                       int* __restrict__ rp) {
    int i = blockIdx.x * 256 + threadIdx.x;
    if (i > N) return;
    int lo = 0, hi = E;
    while (lo < hi) {
        int mid = (lo + hi) >> 1;
        if (rows[mid] < i) lo = mid + 1; else hi = mid;
    }
    rp[i] = lo;
}

// ---------------------------------------------------------------------------
// Wt[n][k] = bf16(W[k][n]), 128x128.
// ---------------------------------------------------------------------------
__global__ __launch_bounds__(256) void transpose_w_k(const float* __restrict__ W,
                                                     uint16_t* __restrict__ Wt) {
    int idx = blockIdx.x * 256 + threadIdx.x;   // 0..16383
    int k = idx >> 7, n = idx & 127;
    Wt[n * FDIM + k] = f2bf(W[k * FDIM + n]);
}

// ---------------------------------------------------------------------------
// reorder_k: per-row ballot counting sort by phase (col >> 13). Writes
// edge2[i] = (full col, f32 val bits) int2, row-major into [rp[r], rp[r+1]).
// Correctness is ORDER-INDEPENDENT downstream (full col stored); the sort
// is purely a locality optimization. Bijection argument: edge at lane l with
// phase p writes position base_p + rank(l in ballot(p)); ranges [base_p,
// base_p+|m_p|) partition [0, deg).
// ---------------------------------------------------------------------------
__global__ __launch_bounds__(256) void reorder_k(const int* __restrict__ rp,
                                                 const int* __restrict__ cols,
                                                 const float* __restrict__ vals,
                                                 int2* __restrict__ edge2, int N) {
    int r    = (blockIdx.x * 256 + threadIdx.x) >> 6;
    int lane = threadIdx.x & 63;
    if (r >= N) return;
    int s = __builtin_amdgcn_readfirstlane(rp[r]);
    int e = __builtin_amdgcn_readfirstlane(rp[r + 1]);
    int deg = e - s;

    if (deg <= 64) {
        bool valid = lane < deg;
        int   c = valid ? cols[s + lane] : 0x7fffffff;
        float v = valid ? vals[s + lane] : 0.f;
        int  ph = c >> PH_SHIFT;               // invalid lanes: huge, never matches
        int base = 0;
        for (int p = 0; p < NPH; ++p) {
            unsigned long long m = __ballot(ph == p);
            int pref = __popcll(m & ((1ull << lane) - 1ull));
            if (ph == p) edge2[s + base + pref] = make_int2(c, __float_as_int(v));
            base += __popcll(m);
        }
    } else if (lane == 0) {
        // rare fallback (Poisson(32) tail beyond 64)
        int b = 0;
        for (int p = 0; p < NPH; ++p)
            for (int i = s; i < e; ++i) {
                int c = cols[i];
                if ((c >> PH_SHIFT) == p) {
                    edge2[s + b] = make_int2(c, __float_as_int(vals[i]));
                    ++b;
                }
            }
    }
}

// ---------------------------------------------------------------------------
// GEMM: C = A @ W via bf16 MFMA 16x16x32 (validated round 3).
// ---------------------------------------------------------------------------
template <int ABF>
__global__ __launch_bounds__(256) void gemm_mfma_k(const void* __restrict__ A_,
                                                   const uint16_t* __restrict__ Wt,
                                                   uint16_t* __restrict__ C, int M) {
    const int t = threadIdx.x;
    const int w = t >> 6;
    const int l = t & 63;
    const int row0 = blockIdx.x * 128 + w * 32;

    f32x4 acc[2][8];
#pragma unroll
    for (int mf = 0; mf < 2; ++mf)
#pragma unroll
        for (int nf = 0; nf < 8; ++nf) acc[mf][nf] = (f32x4)0.f;

    const int lr = l & 15;
    const int kg = l >> 4;

#pragma unroll
    for (int ks = 0; ks < 4; ++ks) {
        const int k0 = ks * 32 + kg * 8;
        short8v a[2];
#pragma unroll
        for (int mf = 0; mf < 2; ++mf) {
            int r = row0 + mf * 16 + lr;
            if (r >= M) r = M - 1;      // safe clamp; stores guarded
            if constexpr (ABF) {
                a[mf] = *(const short8v*)((const uint16_t*)A_ + (size_t)r * FDIM + k0);
            } else {
                const float* ap = (const float*)A_ + (size_t)r * FDIM + k0;
                float4 f0 = *(const float4*)(ap);
                float4 f1 = *(const float4*)(ap + 4);
                uint32_t p0 = pack_bf16(f0.x, f0.y), p1 = pack_bf16(f0.z, f0.w);
                uint32_t p2 = pack_bf16(f1.x, f1.y), p3 = pack_bf16(f1.z, f1.w);
                uint4 u = make_uint4(p0, p1, p2, p3);
                a[mf] = *(short8v*)&u;
            }
        }
#pragma unroll
        for (int nf = 0; nf < 8; ++nf) {
            short8v b = *(const short8v*)(Wt + (size_t)(nf * 16 + lr) * FDIM + k0);
            acc[0][nf] = __builtin_amdgcn_mfma_f32_16x16x32_bf16(a[0], b, acc[0][nf], 0, 0, 0);
            acc[1][nf] = __builtin_amdgcn_mfma_f32_16x16x32_bf16(a[1], b, acc[1][nf], 0, 0, 0);
        }
    }

    const int colpar = l & 1;
#pragma unroll
    for (int mf = 0; mf < 2; ++mf) {
#pragma unroll
        for (int nf = 0; nf < 8; ++nf) {
            int col = nf * 16 + lr;
#pragma unroll
            for (int j = 0; j < 4; ++j) {
                float v = acc[mf][nf][j];
                float pv = __shfl_xor(v, 1);
                int row = row0 + mf * 16 + kg * 4 + j;
                if (!colpar && row < M) {
                    *(uint32_t*)(C + (size_t)row * FDIM + col) = pack_bf16(v, pv);
                }
            }
        }
    }
}

// ---------------------------------------------------------------------------
// SPMM v4: one wave = 2 adjacent rows. Lanes 0-31 -> row A, 32-63 -> row B;
// lane f owns features [4f, 4f+4) (one uint2 = 4 bf16 per gather).
// Per iteration each half consumes 2 edges: 2 edge2 loads + 2 uint2 gathers
// in flight -> 1 VMEM instr/edge. Wave-uniform SGPR cursors; any edge order
// is correct (full col stored); phase-sorted order gives L2 locality.
// ---------------------------------------------------------------------------
template <int RELU, int OBF>
__global__ __launch_bounds__(256) void spmm4_k(const int* __restrict__ rp,
                                               const int2* __restrict__ edge2,
                                               const uint32_t* __restrict__ X, // bf16x2 rows
                                               const float* __restrict__ bias,
                                               void* __restrict__ out, int N) {
    const int wid  = (blockIdx.x * 256 + threadIdx.x) >> 6;   // 0..N/2-1
    const int lane = threadIdx.x & 63;
    const int half = lane >> 5;
    const int f    = lane & 31;
    const int rA   = 2 * wid;

    const int sA = __builtin_amdgcn_readfirstlane(rp[rA]);
    const int sB = __builtin_amdgcn_readfirstlane(rp[rA + 1]);
    const int eB = __builtin_amdgcn_readfirstlane(rp[rA + 2]);
    const int eA = sB;

    float a0 = 0.f, a1 = 0.f, a2 = 0.f, a3 = 0.f;
    int iA = sA, iB = sB;

    while (iA < eA || iB < eB) {
        // my half's cursor and bounds (per-lane select of uniform values)
        int  i0 = half ? iB : iA;
        int  ee = half ? eB : eA;
        bool q0 = i0 < ee, q1 = (i0 + 1) < ee;
        int  x0 = q0 ? i0 : 0;              // edge2[0] always valid (E>0)
        int  x1 = q1 ? (i0 + 1) : 0;
        int2 ev0 = edge2[x0];
        int2 ev1 = edge2[x1];
        float v0 = q0 ? __int_as_float(ev0.y) : 0.f;
        float v1 = q1 ? __int_as_float(ev1.y) : 0.f;
        uint2 u0 = *(const uint2*)(X + (size_t)ev0.x * 64 + 2 * f);
        uint2 u1 = *(const uint2*)(X + (size_t)ev1.x * 64 + 2 * f);
        a0 = fmaf(v0, bflo(u0.x), a0); a1 = fmaf(v0, bfhi(u0.x), a1);
        a2 = fmaf(v0, bflo(u0.y), a2); a3 = fmaf(v0, bfhi(u0.y), a3);
        a0 = fmaf(v1, bflo(u1.x), a0); a1 = fmaf(v1, bfhi(u1.x), a1);
        a2 = fmaf(v1, bflo(u1.y), a2); a3 = fmaf(v1, bfhi(u1.y), a3);
        iA = (iA + 2 < eA) ? iA + 2 : eA;   // advance both (uniform)
        iB = (iB + 2 < eB) ? iB + 2 : eB;
    }

    const int r = rA + half;
    float4 bb = *(const float4*)(bias + 4 * f);
    a0 += bb.x; a1 += bb.y; a2 += bb.z; a3 += bb.w;
    if (RELU) {
        a0 = fmaxf(a0, 0.f); a1 = fmaxf(a1, 0.f);
        a2 = fmaxf(a2, 0.f); a3 = fmaxf(a3, 0.f);
    }
    if constexpr (OBF) {
        uint2 o = make_uint2(pack_bf16(a0, a1), pack_bf16(a2, a3));
        *(uint2*)((uint32_t*)out + (size_t)r * 64 + 2 * f) = o;
    } else {
        *(float4*)((float*)out + (size_t)r * FDIM + 4 * f) =
            make_float4(a0, a1, a2, a3);
    }
}

// ---------------------------------------------------------------------------
extern "C" void kernel_launch(void* const* d_in, const int* in_sizes, int n_in,
                              void* d_out, int out_size, void* d_ws, size_t ws_size,
                              hipStream_t stream) {
    const float* features = (const float*)d_in[0];
    const int*   adj_rows = (const int*)d_in[1];
    const int*   adj_cols = (const int*)d_in[2];
    const float* adj_vals = (const float*)d_in[3];
    const float* W1       = (const float*)d_in[4];
    const float* b1       = (const float*)d_in[5];
    const float* W2       = (const float*)d_in[6];
    const float* b2       = (const float*)d_in[7];

    const int N = in_sizes[0] / FDIM;    // 100000 (even)
    const int E = in_sizes[1];           // 3200000
    float* out = (float*)d_out;

    // ws layout (~77.3 MB; >=103 MB proven available in round 1)
    char* ws = (char*)d_ws;
    int*      rp    = (int*)ws;                               // (N+1)*4
    size_t    rp_b  = (((size_t)(N + 1) * 4) + 255) & ~(size_t)255;
    int2*     edge2 = (int2*)(ws + rp_b);                     // E*8 = 25.6 MB
    size_t    e2_b  = (((size_t)E * 8) + 255) & ~(size_t)255;
    uint16_t* XWb   = (uint16_t*)((char*)edge2 + e2_b);       // N*128 bf16 = 25.6 MB
    uint16_t* Hb    = XWb + (size_t)N * FDIM;                 // N*128 bf16 = 25.6 MB
    uint16_t* W1t   = Hb + (size_t)N * FDIM;                  // 32 KB
    uint16_t* W2t   = W1t + FDIM * FDIM;                      // 32 KB

    const int nblk_gemm = (N + 127) / 128;
    const int nblk_spmm = (N / 2 + 3) / 4;    // one wave per row-pair

    // --- preprocessing ---
    build_row_ptr_k<<<(N + 256) / 256, 256, 0, stream>>>(adj_rows, E, N, rp);
    transpose_w_k<<<64, 256, 0, stream>>>(W1, W1t);
    transpose_w_k<<<64, 256, 0, stream>>>(W2, W2t);
    reorder_k<<<(int)(((size_t)N * 64 + 255) / 256), 256, 0, stream>>>(
        rp, adj_cols, adj_vals, edge2, N);
    // --- layer 1 ---
    gemm_mfma_k<0><<<nblk_gemm, 256, 0, stream>>>((const void*)features, W1t, XWb, N);
    spmm4_k<1, 1><<<nblk_spmm, 256, 0, stream>>>(rp, edge2, (const uint32_t*)XWb,
                                                 b1, (void*)Hb, N);
    // --- layer 2 ---
    gemm_mfma_k<1><<<nblk_gemm, 256, 0, stream>>>((const void*)Hb, W2t, XWb, N);
    spmm4_k<0, 0><<<nblk_spmm, 256, 0, stream>>>(rp, edge2, (const uint32_t*)XWb,
                                                 b2, (void*)out, N);
}